// Round 2
// baseline (335.455 us; speedup 1.0000x reference)
//
#include <hip/hip_runtime.h>

#define PDIM 1024

typedef float fx4 __attribute__((ext_vector_type(4)));   // native vec4 for
                                                         // nontemporal loads

// One block per row i. 256 threads = 4 waves = 16 teams of 16 lanes.
//  setup : stage nei (int4/thread), ballot-compact active j list, team-0
//          computes hib = hidden[i]·Wi + b
//  phase A: team per 8-row chunk of the active list — 16 independent VMEM
//           loads in flight, then a transpose-butterfly reduce (8 shuffles
//           per 8 rows instead of 4 per row; lane q ends with row q&7's dot)
//  phase B: exact reference masked-softmax semantics
//  phase C: team per active row j — acc += attn[j] * hidden[j], cross-team
//           LDS reduce
__global__ __launch_bounds__(256, 4) void social_row(
    const float* __restrict__ hidden,
    const float* __restrict__ rela,
    const int*   __restrict__ nei,
    const float* __restrict__ W,
    const float* __restrict__ bptr,
    float* __restrict__ out)
{
    __shared__ float s_pos[PDIM];    // scores → attn (in place)
    __shared__ int   s_list[PDIM];   // compacted active j
    __shared__ float s_part[PDIM];   // 16 teams × 64 dims
    __shared__ float s_red[8];
    __shared__ int   s_wsum[4];
    __shared__ float s_hib;

    const int i    = blockIdx.x;
    const int tid  = threadIdx.x;
    const int lane = tid & 63;
    const int wave = tid >> 6;      // 0..3
    const int q    = tid & 15;      // float4 chunk of the 64-dim
    const int tm   = tid >> 4;      // team 0..15 (block-wide)

    // ---- stage nei + init scores to the masked value ----------------------
    const int4 nv = reinterpret_cast<const int4*>(nei + ((size_t)i << 10))[tid];
    const int a0 = nv.x > 0, a1 = nv.y > 0, a2 = nv.z > 0, a3 = nv.w > 0;
    reinterpret_cast<float4*>(s_pos)[tid] =
        make_float4(-1e-6f, -1e-6f, -1e-6f, -1e-6f);

    // per-lane W chunks: Wr = W[0:64], Wi = W[64:128], Wj = W[128:192]
    const float4 wr = reinterpret_cast<const float4*>(W)[q];
    const float4 wj = reinterpret_cast<const float4*>(W)[32 + q];

    // ---- hib = hidden[i]·Wi + b  (team 0, wave 0) -------------------------
    if (tid < 16) {
        float4 hv = reinterpret_cast<const float4*>(hidden)[(i << 4) + tid];
        float4 wi = reinterpret_cast<const float4*>(W)[16 + tid];
        float p = hv.x * wi.x + hv.y * wi.y + hv.z * wi.z + hv.w * wi.w;
        p += __shfl_xor(p, 1); p += __shfl_xor(p, 2);
        p += __shfl_xor(p, 4); p += __shfl_xor(p, 8);
        if (tid == 0) s_hib = p + bptr[0];
    }

    // ---- compact the active-j list via ballot prefix ----------------------
    const unsigned long long b0 = __ballot(a0);
    const unsigned long long b1 = __ballot(a1);
    const unsigned long long b2 = __ballot(a2);
    const unsigned long long b3 = __ballot(a3);
    const int t0 = __popcll(b0), t1 = __popcll(b1),
              t2 = __popcll(b2), t3 = __popcll(b3);
    if (lane == 0) s_wsum[wave] = t0 + t1 + t2 + t3;
    __syncthreads();

    int woff = 0;
#pragma unroll
    for (int u = 0; u < 4; ++u) woff += (u < wave) ? s_wsum[u] : 0;
    const int nAct = s_wsum[0] + s_wsum[1] + s_wsum[2] + s_wsum[3];
    const unsigned long long lt = (1ull << lane) - 1ull;   // lanes below me
    const int jb = tid << 2;
    if (a0) s_list[woff + __popcll(b0 & lt)] = jb;
    if (a1) s_list[woff + t0 + __popcll(b1 & lt)] = jb + 1;
    if (a2) s_list[woff + t0 + t1 + __popcll(b2 & lt)] = jb + 2;
    if (a3) s_list[woff + t0 + t1 + t2 + __popcll(b3 & lt)] = jb + 3;
    __syncthreads();

    const float hib = s_hib;
    const float4* h4 = reinterpret_cast<const float4*>(hidden);
    const fx4* r4 = reinterpret_cast<const fx4*>(rela) + ((size_t)i << 14);

    // ---- phase A: batched fused scores over active rows -------------------
    // Team tm handles 8-entry chunks of the compacted list. All 16 loads of
    // a chunk are independent (HBM latency hidden); the 64-dim dot spread
    // over 16 lanes is reduced with a transpose-butterfly: after masks
    // 1,2,4,8 lane q holds the full dot for local row (q&7).
    const int nChunk = (nAct + 7) >> 3;
    for (int c = tm; c < nChunk; c += 16) {
        const int ce = c << 3;
        const int cnt = min(8, nAct - ce);
        float p[8];
        if (cnt == 8) {
            int jl[8];
#pragma unroll
            for (int t = 0; t < 8; ++t) jl[t] = s_list[ce + t];
#pragma unroll
            for (int t = 0; t < 8; ++t) {
                const fx4 rv =
                    __builtin_nontemporal_load(r4 + (jl[t] << 4) + q);
                const float4 hv = h4[(jl[t] << 4) + q];
                p[t] = rv.x * wr.x + rv.y * wr.y + rv.z * wr.z + rv.w * wr.w
                     + hv.x * wj.x + hv.y * wj.y + hv.z * wj.z + hv.w * wj.w;
            }
        } else {
            int jl[8];
#pragma unroll
            for (int t = 0; t < 8; ++t)
                jl[t] = s_list[ce + ((t < cnt) ? t : 0)];
#pragma unroll
            for (int t = 0; t < 8; ++t) {
                if (t < cnt) {
                    const fx4 rv =
                        __builtin_nontemporal_load(r4 + (jl[t] << 4) + q);
                    const float4 hv = h4[(jl[t] << 4) + q];
                    p[t] = rv.x * wr.x + rv.y * wr.y + rv.z * wr.z + rv.w * wr.w
                         + hv.x * wj.x + hv.y * wj.y + hv.z * wj.z + hv.w * wj.w;
                } else {
                    p[t] = 0.0f;
                }
            }
        }

        // transpose-butterfly reduce (8 shuffles total for 8 rows)
        float s, v0, v1, v2, v3;
        s  = (q & 1) ? p[0] : p[1];  s = __shfl_xor(s, 1);
        v0 = ((q & 1) ? p[1] : p[0]) + s;
        s  = (q & 1) ? p[2] : p[3];  s = __shfl_xor(s, 1);
        v1 = ((q & 1) ? p[3] : p[2]) + s;
        s  = (q & 1) ? p[4] : p[5];  s = __shfl_xor(s, 1);
        v2 = ((q & 1) ? p[5] : p[4]) + s;
        s  = (q & 1) ? p[6] : p[7];  s = __shfl_xor(s, 1);
        v3 = ((q & 1) ? p[7] : p[6]) + s;

        s  = (q & 2) ? v0 : v1;  s = __shfl_xor(s, 2);
        v0 = ((q & 2) ? v1 : v0) + s;
        s  = (q & 2) ? v2 : v3;  s = __shfl_xor(s, 2);
        v1 = ((q & 2) ? v3 : v2) + s;

        s  = (q & 4) ? v0 : v1;  s = __shfl_xor(s, 4);
        v0 = ((q & 4) ? v1 : v0) + s;

        v0 += __shfl_xor(v0, 8);          // lane q now holds row (q&7)'s dot

        if (q < cnt) {
            const int jq = s_list[ce + q];       // re-read: avoids jl[q] scratch
            const float sc = v0 + hib;
            s_pos[jq] = (sc == 0.0f) ? -1e-6f : sc;   // Pos==0 pin
        }
    }
    __syncthreads();

    // ---- phase B: softmax over all 1024 pos values ------------------------
    const float4 p4 = reinterpret_cast<const float4*>(s_pos)[tid];
    float m = fmaxf(fmaxf(p4.x, p4.y), fmaxf(p4.z, p4.w));
#pragma unroll
    for (int d = 1; d < 64; d <<= 1) m = fmaxf(m, __shfl_xor(m, d));
    if (lane == 0) s_red[wave] = m;
    __syncthreads();
    const float M = fmaxf(fmaxf(s_red[0], s_red[1]), fmaxf(s_red[2], s_red[3]));

    const float x0 = __expf(p4.x - M);
    const float x1 = __expf(p4.y - M);
    const float x2 = __expf(p4.z - M);
    const float x3 = __expf(p4.w - M);
    float ssum = (x0 + x1) + (x2 + x3);
#pragma unroll
    for (int d = 1; d < 64; d <<= 1) ssum += __shfl_xor(ssum, d);
    if (lane == 0) s_red[4 + wave] = ssum;
    __syncthreads();
    const float S = s_red[4] + s_red[5] + s_red[6] + s_red[7];
    const float inv = 1.0f / S;

    float4 attn;
    attn.x = a0 ? x0 * inv : 0.0f;
    attn.y = a1 ? x1 * inv : 0.0f;
    attn.z = a2 ? x2 * inv : 0.0f;
    attn.w = a3 ? x3 * inv : 0.0f;
    reinterpret_cast<float4*>(s_pos)[tid] = attn;
    __syncthreads();

    // ---- phase C: out[i,:] = attn · hidden over active rows only ----------
    float4 acc = make_float4(0.f, 0.f, 0.f, 0.f);
#pragma unroll 4
    for (int e = tm; e < nAct; e += 16) {
        const int j = s_list[e];
        const float a = s_pos[j];
        const float4 hv = h4[(j << 4) + q];
        acc.x += a * hv.x; acc.y += a * hv.y;
        acc.z += a * hv.z; acc.w += a * hv.w;
    }
    reinterpret_cast<float4*>(s_part)[(tm << 4) + q] = acc;
    __syncthreads();

    if (tid < 64) {
        float r = 0.f;
#pragma unroll
        for (int t = 0; t < 16; ++t) r += s_part[(t << 6) + tid];
        out[((size_t)i << 6) + tid] = r;
    }
}

// ---------------------------------------------------------------------------
extern "C" void kernel_launch(void* const* d_in, const int* in_sizes, int n_in,
                              void* d_out, int out_size, void* d_ws, size_t ws_size,
                              hipStream_t stream)
{
    const float* hidden = (const float*)d_in[0];   // (1024, 64) f32
    const float* rela   = (const float*)d_in[1];   // (1024, 1024, 64) f32
    // d_in[2] = corr_index — unused by the reference
    const int*   nei    = (const int*)d_in[3];     // (1024, 1024) i32
    const float* W      = (const float*)d_in[4];   // (192,) f32
    const float* bptr   = (const float*)d_in[5];   // scalar f32
    (void)d_ws; (void)ws_size;

    social_row<<<PDIM, 256, 0, stream>>>(hidden, rela, nei, W, bptr,
                                         (float*)d_out);
}